// Round 1
// baseline (9221.883 us; speedup 1.0000x reference)
//
#include <hip/hip_runtime.h>

typedef __attribute__((ext_vector_type(8))) short short8;
typedef __attribute__((ext_vector_type(4))) float f32x4;
typedef __attribute__((ext_vector_type(4))) int int4v;
typedef __attribute__((ext_vector_type(4))) unsigned short u16x4;
typedef unsigned short u16;

#define T_LEN 256
#define BATCH 64
#define HID   1024
#define GDIM  4128
#define K2    2048

__device__ __forceinline__ u16 f2bf(float f){
  unsigned u = __builtin_bit_cast(unsigned, f);
  return (u16)((u + 0x7fffu + ((u >> 16) & 1u)) >> 16);
}

// ---- prologue kernels -------------------------------------------------------

// Transpose+cast [2048 x 4128] (rows: W_ih then W_hh) -> Wt[col][k] bf16
__global__ __launch_bounds__(1024) void repackW(const float* __restrict__ Wih,
                                                const float* __restrict__ Whh,
                                                u16* __restrict__ Wt)
{
  __shared__ float tile[32][33];
  int k = blockIdx.x * 32 + threadIdx.y;
  int c = blockIdx.y * 32 + threadIdx.x;
  float v = (k < 1024) ? Wih[(size_t)k * GDIM + c]
                       : Whh[(size_t)(k - 1024) * GDIM + c];
  tile[threadIdx.y][threadIdx.x] = v;
  __syncthreads();
  int c2 = blockIdx.y * 32 + threadIdx.y;
  int k2 = blockIdx.x * 32 + threadIdx.x;
  Wt[(size_t)c2 * K2 + k2] = f2bf(tile[threadIdx.x][threadIdx.y]);
}

// x[t*64+b][k] = bf16(emb[tokens[t*64+b]][k]); also mask output
__global__ __launch_bounds__(256) void gatherX(const int* __restrict__ tokens,
                                               const float* __restrict__ emb,
                                               u16* __restrict__ x,
                                               float* __restrict__ maskout)
{
  int idx = blockIdx.x;
  int tok = tokens[idx];
  const f32x4* src = (const f32x4*)&emb[(size_t)tok * HID];
  f32x4 v = src[threadIdx.x];
  u16x4 o;
  #pragma unroll
  for (int j = 0; j < 4; ++j) o[j] = f2bf(v[j]);
  *(u16x4*)&x[(size_t)idx * HID + threadIdx.x * 4] = o;
  if (threadIdx.x == 0) maskout[idx] = (tok != 0) ? 1.0f : 0.0f;
}

__global__ __launch_bounds__(256) void biasK(const float* __restrict__ bih0, const float* __restrict__ bhh0,
                                             const float* __restrict__ bih1, const float* __restrict__ bhh1,
                                             float* __restrict__ bias0, float* __restrict__ bias1)
{
  int i = blockIdx.x * 256 + threadIdx.x;
  if (i < GDIM){ bias0[i] = bih0[i] + bhh0[i]; bias1[i] = bih1[i] + bhh1[i]; }
}

__global__ __launch_bounds__(256) void zeroK(int4v* __restrict__ p)
{
  int4v z = {0,0,0,0};
  p[blockIdx.x * 256 + threadIdx.x] = z;
}

// ---- recurrent step: matmul (both layers pipelined) -------------------------
// grid 172: WGs 0..85 layer0 (t=s), 86..171 layer1 (t=s-1); 48 cols each.
// block 768 = 12 waves = 4 mtiles x 3 ntiles; MFMA 16x16x32 bf16, K=2048.
__global__ __launch_bounds__(768) void stepA(
    const u16* __restrict__ Wt0, const u16* __restrict__ Wt1,
    const float* __restrict__ bias0, const float* __restrict__ bias1,
    const u16* __restrict__ x, const u16* __restrict__ h1,
    const u16* __restrict__ h2pp, const u16* __restrict__ zerob,
    float* __restrict__ gates0, float* __restrict__ gates1, int s)
{
  int w = blockIdx.x;
  int L = (w >= 86) ? 1 : 0;
  int wl = w - L * 86;
  int t = L ? (s - 1) : s;
  if (t < 0 || t >= T_LEN) return;
  int colbase = wl * 48;
  const u16* Wt = (L ? Wt1 : Wt0) + (size_t)colbase * K2;
  const float* bias = L ? bias1 : bias0;
  float* gates = L ? gates1 : gates0;
  const u16* p1 = L ? (h1 + (size_t)t * (BATCH * HID))
                    : (x  + (size_t)t * (BATCH * HID));
  const u16* p2;
  if (L) p2 = (t == 0) ? zerob : (h2pp + (size_t)((t - 1) & 1) * (BATCH * HID));
  else   p2 = (t == 0) ? zerob : (h1   + (size_t)(t - 1) * (BATCH * HID));

  __shared__ __align__(16) u16 Bs[48][1032];   // 48 cols x 1024 k (half), padded

  int tid  = threadIdx.x;
  int wave = tid >> 6, lane = tid & 63;
  int mtile = wave & 3, ntile = wave >> 2;     // ntile 0..2
  int lo = lane & 15, hi = lane >> 4;
  int brow = mtile * 16 + lo;                  // batch row 0..63
  const u16* pa1 = p1 + (size_t)brow * HID;
  const u16* pa2 = p2 + (size_t)brow * HID;
  int bcol = ntile * 16 + lo;                  // local col 0..47
  f32x4 acc = {0.f, 0.f, 0.f, 0.f};

  for (int ph = 0; ph < 2; ++ph) {
    __syncthreads();
    // stage 48 x 1024 bf16 weight half-slice into LDS (coalesced 16B chunks)
    for (int i = tid; i < 48 * 128; i += 768) {
      int row = i >> 7;
      int off = (i & 127) << 3;
      *(int4v*)&Bs[row][off] =
          *(const int4v*)&Wt[(size_t)row * K2 + ph * 1024 + off];
    }
    __syncthreads();
    const u16* pa = ph ? pa2 : pa1;
    #pragma unroll 4
    for (int ks = 0; ks < 32; ++ks) {
      int k0 = ks * 32 + hi * 8;
      short8 a = *(const short8*)(pa + k0);
      short8 b = *(const short8*)&Bs[bcol][k0];
      acc = __builtin_amdgcn_mfma_f32_16x16x32_bf16(a, b, acc, 0, 0, 0);
    }
  }
  int colg = colbase + ntile * 16 + lo;
  float bv = bias[colg];
  #pragma unroll
  for (int j = 0; j < 4; ++j) {
    int br = mtile * 16 + hi * 4 + j;          // C/D: col=lane&15, row=(lane>>4)*4+j
    gates[(size_t)br * GDIM + colg] = acc[j] + bv;
  }
}

// ---- recurrent step: gating nonlinearity (both layers) ----------------------
__global__ __launch_bounds__(256) void stepB(
    const float* __restrict__ gates0, const float* __restrict__ gates1,
    float* __restrict__ c0, float* __restrict__ c1,
    u16* __restrict__ h1, u16* __restrict__ h2pp,
    float* __restrict__ out, int s)
{
  int b = blockIdx.x, tid = threadIdx.x;
  __shared__ float sg[32];
  for (int L = 0; L < 2; ++L) {
    int t = L ? (s - 1) : s;
    if (t < 0 || t >= T_LEN) continue;        // uniform across block
    __syncthreads();
    const float* g = (L ? gates1 : gates0) + (size_t)b * GDIM;
    if (tid < 32) sg[tid] = g[tid];
    __syncthreads();
    int e = tid * 4;            // 4 h-elements per thread, same chunk
    int n = e >> 6;
    int k = e & 63;
    float m1 = -1e30f, m2 = -1e30f;
    #pragma unroll
    for (int i = 0; i < 16; ++i){ m1 = fmaxf(m1, sg[i]); m2 = fmaxf(m2, sg[16 + i]); }
    float s1 = 0.f, s2 = 0.f, cu1 = 0.f, cu2 = 0.f;
    #pragma unroll
    for (int i = 0; i < 16; ++i){
      float e1 = __expf(sg[i] - m1), e2 = __expf(sg[16 + i] - m2);
      s1 += e1; s2 += e2;
      if (i <= n){ cu1 += e1; cu2 += e2; }
    }
    float cin = 1.f - cu1 / s1;     // cingate for chunk n
    float cf  = cu2 / s2;           // cforgetgate for chunk n
    float ov  = cf * cin;
    const float* gr = g + 32 + n * 64 + k;
    f32x4 og4 = *(const f32x4*)(gr);
    f32x4 ce4 = *(const f32x4*)(gr + 1024);
    f32x4 in4 = *(const f32x4*)(gr + 2048);
    f32x4 fg4 = *(const f32x4*)(gr + 3072);
    float* cbuf = (L ? c1 : c0) + (size_t)b * HID + e;
    f32x4 cx;
    if (t == 0) { cx = f32x4{0.f,0.f,0.f,0.f}; } else { cx = *(const f32x4*)cbuf; }
    f32x4 hy;
    #pragma unroll
    for (int j = 0; j < 4; ++j){
      float ogv = 1.f / (1.f + __expf(-og4[j]));
      float inv = 1.f / (1.f + __expf(-in4[j]));
      float fgv = 1.f / (1.f + __expf(-fg4[j]));
      float cev = tanhf(ce4[j]);
      float fga = fgv * ov + (cf - ov);
      float iga = inv * ov + (cin - ov);
      float cy  = fga * cx[j] + iga * cev;
      cx[j] = cy;
      hy[j] = ogv * tanhf(cy);
    }
    *(f32x4*)cbuf = cx;
    if (L == 0){
      u16x4 hb;
      #pragma unroll
      for (int j = 0; j < 4; ++j) hb[j] = f2bf(hy[j]);
      *(u16x4*)&h1[(size_t)t * (BATCH * HID) + b * HID + e] = hb;
    } else {
      *(f32x4*)&out[((size_t)t * BATCH + b) * HID + e] = hy;
      u16x4 hb;
      #pragma unroll
      for (int j = 0; j < 4; ++j) hb[j] = f2bf(hy[j]);
      *(u16x4*)&h2pp[(size_t)(t & 1) * (BATCH * HID) + b * HID + e] = hb;
    }
  }
}

// ---- launch -----------------------------------------------------------------

extern "C" void kernel_launch(void* const* d_in, const int* in_sizes, int n_in,
                              void* d_out, int out_size, void* d_ws, size_t ws_size,
                              hipStream_t stream)
{
  (void)in_sizes; (void)n_in; (void)out_size; (void)ws_size;
  const int*   tokens = (const int*)d_in[0];
  const float* emb    = (const float*)d_in[1];
  const float* Wih0   = (const float*)d_in[2];
  const float* bih0   = (const float*)d_in[3];
  const float* Whh0   = (const float*)d_in[4];
  const float* bhh0   = (const float*)d_in[5];
  const float* Wih1   = (const float*)d_in[6];
  const float* bih1   = (const float*)d_in[7];
  const float* Whh1   = (const float*)d_in[8];
  const float* bhh1   = (const float*)d_in[9];
  float* out = (float*)d_out;

  char* ws = (char*)d_ws;
  // byte offsets (all 16B aligned)
  u16*   Wt0    = (u16*)(ws);                    // 4128*2048*2 = 16,908,288
  u16*   Wt1    = (u16*)(ws + 16908288);         // 16,908,288
  u16*   x      = (u16*)(ws + 33816576);         // 16384*1024*2 = 33,554,432
  u16*   h1     = (u16*)(ws + 67371008);         // 33,554,432
  float* bias0  = (float*)(ws + 100925440);      // 16,512
  float* bias1  = (float*)(ws + 100941952);      // 16,512
  float* gates0 = (float*)(ws + 100958464);      // 64*4128*4 = 1,056,768
  float* gates1 = (float*)(ws + 102015232);      // 1,056,768
  float* c0     = (float*)(ws + 103072000);      // 64*1024*4 = 262,144
  float* c1     = (float*)(ws + 103334144);      // 262,144
  u16*   zerob  = (u16*)(ws + 103596288);        // 131,072   (zeroed)
  u16*   h2pp   = (u16*)(ws + 103727360);        // 262,144   (zeroed, adjacent)
  // total = 103,989,504 bytes

  repackW<<<dim3(64,129), dim3(32,32), 0, stream>>>(Wih0, Whh0, Wt0);
  repackW<<<dim3(64,129), dim3(32,32), 0, stream>>>(Wih1, Whh1, Wt1);
  gatherX<<<16384, 256, 0, stream>>>(tokens, emb, x, out + 16777216);
  biasK<<<17, 256, 0, stream>>>(bih0, bhh0, bih1, bhh1, bias0, bias1);
  zeroK<<<96, 256, 0, stream>>>((int4v*)zerob);  // zerob + h2pp contiguous

  for (int s = 0; s <= 256; ++s){
    stepA<<<172, 768, 0, stream>>>(Wt0, Wt1, bias0, bias1, x, h1, h2pp, zerob,
                                   gates0, gates1, s);
    stepB<<<64, 256, 0, stream>>>(gates0, gates1, c0, c1, h1, h2pp, out, s);
  }
}